// Round 12
// baseline (37.505 us; speedup 1.0000x reference)
//
#include <hip/hip_runtime.h>
#include <float.h>

#define NB 68                 // padded bins (64 + 2*2)
#define NJ (NB * NB)          // 4624 joint bins
#define HTHREADS 512
#define MMBLK 125             // minmax blocks per batch (125*1024 = 128000 float4s)
#define SCALE 2097152.0f      // 2^21 fixed-point scale
#define INV_SCALE (1.0 / 2097152.0)

// ws layout (bytes):
// [64 .. 64+2*128*16)    P: per-block minmax partials, float4 {smx,smn,tmx,tmn}
// [4160 .. +2*NJ*8)      J: u64 fixed-point joint totals [b][NJ]
// [78144 .. +2*250*NJ*4) H: per-block u32 histograms [b*nblk+blk][NJ]

// Kernel 1: minmax block partials. One float4 of src+tgt per thread (all
// loads in flight), block reduce, one plain float4 store. No atomics.
__global__ __launch_bounds__(1024) void k_prep(const float* __restrict__ src,
                                               const float* __restrict__ tgt,
                                               float4* __restrict__ P, int n4) {
    __shared__ float red[16][4];
    const int b = blockIdx.y;
    const int i = blockIdx.x * 1024 + threadIdx.x;
    float smx = -FLT_MAX, smn = FLT_MAX, tmx = -FLT_MAX, tmn = FLT_MAX;
    if (i < n4) {
        float4 v = ((const float4*)src)[(size_t)b * n4 + i];
        float4 w = ((const float4*)tgt)[(size_t)b * n4 + i];
        smx = fmaxf(fmaxf(v.x, v.y), fmaxf(v.z, v.w));
        smn = fminf(fminf(v.x, v.y), fminf(v.z, v.w));
        tmx = fmaxf(fmaxf(w.x, w.y), fmaxf(w.z, w.w));
        tmn = fminf(fminf(w.x, w.y), fminf(w.z, w.w));
    }
#pragma unroll
    for (int m = 1; m < 64; m <<= 1) {
        smx = fmaxf(smx, __shfl_xor(smx, m));
        smn = fminf(smn, __shfl_xor(smn, m));
        tmx = fmaxf(tmx, __shfl_xor(tmx, m));
        tmn = fminf(tmn, __shfl_xor(tmn, m));
    }
    const int wave = threadIdx.x >> 6;
    if ((threadIdx.x & 63) == 0) {
        red[wave][0] = smx;
        red[wave][1] = smn;
        red[wave][2] = tmx;
        red[wave][3] = tmn;
    }
    __syncthreads();
    if (threadIdx.x == 0) {
#pragma unroll
        for (int k = 1; k < 16; ++k) {
            smx = fmaxf(smx, red[k][0]);
            smn = fminf(smn, red[k][1]);
            tmx = fmaxf(tmx, red[k][2]);
            tmn = fminf(tmn, red[k][3]);
        }
        P[b * 128 + blockIdx.x] = make_float4(smx, smn, tmx, tmn);
    }
}

__device__ __forceinline__ float bspl(float d) {
    float ad = fabsf(d);
    float a = (3.0f * ad * ad * ad - 6.0f * ad * ad + 4.0f) * (1.0f / 6.0f);
    float t = 2.0f - ad;
    float c = t * t * t * (1.0f / 6.0f);
    return ad < 1.0f ? a : (ad < 2.0f ? c : 0.0f);
}

__device__ __forceinline__ void vox1(float sv, float tv, unsigned* jh,
                                     float spad, float sinv, float tpad,
                                     float tinv) {
    float posS = (sv - spad) * sinv;
    float fS = floorf(posS);
    fS = fminf(fmaxf(fS, 2.0f), 65.0f);
    int si = (int)fS - 1;
    float dS = posS - fS;
    float a[4] = {bspl(dS + 1.0f), bspl(dS), bspl(dS - 1.0f), bspl(dS - 2.0f)};

    float posT = (tv - tpad) * tinv;
    float fT = floorf(posT);
    fT = fminf(fmaxf(fT, 2.0f), 65.0f);
    int ti = (int)fT - 1;
    float dT = posT - fT;
    float bb[4] = {bspl(dT + 1.0f), bspl(dT), bspl(dT - 1.0f), bspl(dT - 2.0f)};

    unsigned* base = jh + si * NB + ti;
#pragma unroll
    for (int r = 0; r < 4; ++r) {
#pragma unroll
        for (int c = 0; c < 4; ++c) {
            unsigned q = (unsigned)(a[r] * bb[c] * SCALE + 0.5f);
            atomicAdd(&base[r * NB + c], q);
        }
    }
}

// Kernel 2: inline minmax reduce (from P, 2 waves) -> LDS u32 joint hist.
// Copies are LANE-interleaved (copy = lane&1): within one ds_add the even
// and odd lanes land NJ apart (NJ%32==16 -> bank+16), so same-bin lane
// pairs stop conflicting. 1 float4/thread, ~2 blocks/CU (74KB LDS/CU).
// Plain coalesced u32 flush; per-copy max 2048 voxels * 0.4444 * 2^21 =
// 1.9e9 < 2^32.
__global__ __launch_bounds__(HTHREADS) void k_hist(
    const float* __restrict__ src, const float* __restrict__ tgt,
    const float4* __restrict__ P, unsigned* __restrict__ H, int n4,
    int nblk) {
    __shared__ unsigned lh[2 * NJ];
    __shared__ float pmm[8], mmv[4];
    const int tid = threadIdx.x;
    const int b = blockIdx.y;

    // inline reduce of the 125 minmax partials (2 waves)
    if (tid < 128) {
        float smx = -FLT_MAX, smn = FLT_MAX, tmx = -FLT_MAX, tmn = FLT_MAX;
        if (tid < MMBLK) {
            float4 v = P[b * 128 + tid];
            smx = v.x; smn = v.y; tmx = v.z; tmn = v.w;
        }
#pragma unroll
        for (int m = 1; m < 64; m <<= 1) {
            smx = fmaxf(smx, __shfl_xor(smx, m));
            smn = fminf(smn, __shfl_xor(smn, m));
            tmx = fmaxf(tmx, __shfl_xor(tmx, m));
            tmn = fminf(tmn, __shfl_xor(tmn, m));
        }
        if ((tid & 63) == 0) {
            int w = tid >> 6;
            pmm[w * 4 + 0] = smx;
            pmm[w * 4 + 1] = smn;
            pmm[w * 4 + 2] = tmx;
            pmm[w * 4 + 3] = tmn;
        }
    }
    // zero LDS hist concurrently
    uint4* z4 = (uint4*)lh;
    const uint4 zz = make_uint4(0u, 0u, 0u, 0u);
    for (int i = tid; i < (2 * NJ) / 4; i += HTHREADS) z4[i] = zz;
    __syncthreads();
    if (tid == 0) {
        mmv[0] = fmaxf(pmm[0], pmm[4]);   // smx
        mmv[1] = fminf(pmm[1], pmm[5]);   // smn
        mmv[2] = fmaxf(pmm[2], pmm[6]);   // tmx
        mmv[3] = fminf(pmm[3], pmm[7]);   // tmn
    }
    __syncthreads();

    const float sbw = (mmv[0] - mmv[1]) * (1.0f / 64.0f);
    const float tbw = (mmv[2] - mmv[3]) * (1.0f / 64.0f);
    const float sinv = 1.0f / sbw, tinv = 1.0f / tbw;
    const float spad = mmv[1] - 2.0f * sbw;
    const float tpad = mmv[3] - 2.0f * tbw;

    unsigned* jh = lh + (tid & 1) * NJ;    // lane-interleaved copies
    const int i0 = blockIdx.x * HTHREADS + tid;
    if (i0 < n4) {
        float4 sA = ((const float4*)src)[(size_t)b * n4 + i0];
        float4 tA = ((const float4*)tgt)[(size_t)b * n4 + i0];
        vox1(sA.x, tA.x, jh, spad, sinv, tpad, tinv);
        vox1(sA.y, tA.y, jh, spad, sinv, tpad, tinv);
        vox1(sA.z, tA.z, jh, spad, sinv, tpad, tinv);
        vox1(sA.w, tA.w, jh, spad, sinv, tpad, tinv);
    }
    __syncthreads();

    unsigned* Hb = H + (size_t)(b * nblk + blockIdx.x) * NJ;
    for (int i = tid; i < NJ; i += HTHREADS) Hb[i] = lh[i] + lh[NJ + i];
}

// Kernel 3: nblk-way per-bin sum with MLP by construction. 256 threads =
// 32 bins x 8 chunks of 32 rows; each thread issues up to 32 INDEPENDENT
// loads (fully unrolled), LDS u64 tree per bin, coalesced J write.
// Integer addition exact -> J bit-identical regardless of partition.
__global__ __launch_bounds__(256) void k_reduce(const unsigned* __restrict__ H,
                                                unsigned long long* __restrict__ J,
                                                int nblk) {
    __shared__ unsigned long long part[8][32];
    const int b = blockIdx.y;
    const int binL = threadIdx.x & 31;          // bin within tile
    const int chunk = threadIdx.x >> 5;         // 0..7 -> rows chunk*32..+31
    const int bin = blockIdx.x * 32 + binL;
    const unsigned* Hb = H + (size_t)b * nblk * NJ;

    unsigned long long s = 0ull;
    if (bin < NJ) {
        const int r0 = chunk * 32;
#pragma unroll
        for (int k = 0; k < 32; ++k) {
            int r = r0 + k;
            if (r < nblk) s += Hb[(size_t)r * NJ + bin];
        }
    }
    part[chunk][binL] = s;
    __syncthreads();
    if (threadIdx.x < 32 && bin < NJ) {
        unsigned long long t = part[0][binL];
#pragma unroll
        for (int c = 1; c < 8; ++c) t += part[c][binL];
        J[(size_t)b * NJ + bin] = t;
    }
}

// Kernel 4: normalize (1 block per batch).
__global__ __launch_bounds__(1024) void k_final(
    const unsigned long long* __restrict__ J, float* __restrict__ out) {
    __shared__ float jf[NJ];
    __shared__ float rs[NB], cs[NB];
    __shared__ float red[16];
    const int b = blockIdx.x, tid = threadIdx.x;
    const unsigned long long* Jb = J + (size_t)b * NJ;

    float part = 0.0f;
    for (int i = tid; i < NJ; i += 1024) {
        float f = (float)((double)Jb[i] * INV_SCALE);
        jf[i] = f;
        part += f;
    }
#pragma unroll
    for (int m = 1; m < 64; m <<= 1) part += __shfl_xor(part, m);
    if ((tid & 63) == 0) red[tid >> 6] = part;
    __syncthreads();

    if (tid < NB) {                      // row sums -> source hist
        float s = 0.0f;
        for (int j = 0; j < NB; ++j) s += jf[tid * NB + j];
        rs[tid] = s;
    }
    if (tid >= 128 && tid < 128 + NB) {  // col sums -> target hist
        int c = tid - 128;
        float s = 0.0f;
        for (int r = 0; r < NB; ++r) s += jf[r * NB + c];
        cs[c] = s;
    }
    __syncthreads();

    float jsum = 0.0f;
#pragma unroll
    for (int k = 0; k < 16; ++k) jsum += red[k];
    float ssum = 0.0f, tsum = 0.0f;
    for (int k = 0; k < NB; ++k) ssum += rs[k];
    for (int k = 0; k < NB; ++k) tsum += cs[k];
    const float sden = fmaxf(ssum, 1e-8f);
    const float tden = fmaxf(tsum, 1e-8f);
    const float jden = fmaxf(jsum, 1e-8f);

    if (tid < NB) out[b * NB + tid] = rs[tid] / sden;
    if (tid >= 128 && tid < 128 + NB)
        out[2 * NB + b * NB + (tid - 128)] = cs[tid - 128] / tden;
    for (int i = tid; i < NJ; i += 1024)
        out[4 * NB + b * NJ + i] = jf[i] / jden;
}

extern "C" void kernel_launch(void* const* d_in, const int* in_sizes, int n_in,
                              void* d_out, int out_size, void* d_ws,
                              size_t ws_size, hipStream_t stream) {
    const float* src = (const float*)d_in[0];
    const float* tgt = (const float*)d_in[1];
    float* out = (float*)d_out;
    float4* P = (float4*)((char*)d_ws + 64);
    unsigned long long* J = (unsigned long long*)((char*)d_ws + 4160);
    unsigned* H = (unsigned*)((char*)d_ws + 78144);
    const int n4 = (in_sizes[0] / 2) / 4;          // 128000
    const int hblk = (n4 + HTHREADS - 1) / HTHREADS;   // 250

    k_prep<<<dim3(MMBLK, 2), dim3(1024), 0, stream>>>(src, tgt, P, n4);
    k_hist<<<dim3(hblk, 2), dim3(HTHREADS), 0, stream>>>(src, tgt, P, H, n4,
                                                         hblk);
    k_reduce<<<dim3((NJ + 31) / 32, 2), dim3(256), 0, stream>>>(H, J, hblk);
    k_final<<<dim3(2), dim3(1024), 0, stream>>>(J, out);
}

// Round 13
// 30.676 us; speedup vs baseline: 1.2226x; 1.2226x over previous
//
#include <hip/hip_runtime.h>
#include <float.h>

#define NB 68                 // padded bins (64 + 2*2)
#define NJ (NB * NB)          // 4624 joint bins
#define HBLK 128              // hist blocks per batch
#define HTHREADS 512
#define MMBLK 125             // minmax blocks per batch (125*1024 = 128000 float4s)
#define SCALE 2097152.0f      // 2^21 fixed-point scale
#define INV_SCALE (1.0 / 2097152.0)

// ws layout (bytes):
// [64 .. 64+2*128*16)    P: per-block minmax partials, float4 {smx,smn,tmx,tmn}
// [4160 .. +2*NJ*8)      J: u64 fixed-point joint totals [b][NJ]
// [78144 .. +2*128*NJ*4) H: per-block u32 histograms [b*128+blk][NJ]

// Kernel 1: minmax block partials. One float4 of src+tgt per thread (all
// loads in flight), block reduce, one plain float4 store. No atomics.
__global__ __launch_bounds__(1024) void k_prep(const float* __restrict__ src,
                                               const float* __restrict__ tgt,
                                               float4* __restrict__ P, int n4) {
    __shared__ float red[16][4];
    const int b = blockIdx.y;
    const int i = blockIdx.x * 1024 + threadIdx.x;
    float smx = -FLT_MAX, smn = FLT_MAX, tmx = -FLT_MAX, tmn = FLT_MAX;
    if (i < n4) {
        float4 v = ((const float4*)src)[(size_t)b * n4 + i];
        float4 w = ((const float4*)tgt)[(size_t)b * n4 + i];
        smx = fmaxf(fmaxf(v.x, v.y), fmaxf(v.z, v.w));
        smn = fminf(fminf(v.x, v.y), fminf(v.z, v.w));
        tmx = fmaxf(fmaxf(w.x, w.y), fmaxf(w.z, w.w));
        tmn = fminf(fminf(w.x, w.y), fminf(w.z, w.w));
    }
#pragma unroll
    for (int m = 1; m < 64; m <<= 1) {
        smx = fmaxf(smx, __shfl_xor(smx, m));
        smn = fminf(smn, __shfl_xor(smn, m));
        tmx = fmaxf(tmx, __shfl_xor(tmx, m));
        tmn = fminf(tmn, __shfl_xor(tmn, m));
    }
    const int wave = threadIdx.x >> 6;
    if ((threadIdx.x & 63) == 0) {
        red[wave][0] = smx;
        red[wave][1] = smn;
        red[wave][2] = tmx;
        red[wave][3] = tmn;
    }
    __syncthreads();
    if (threadIdx.x == 0) {
#pragma unroll
        for (int k = 1; k < 16; ++k) {
            smx = fmaxf(smx, red[k][0]);
            smn = fminf(smn, red[k][1]);
            tmx = fmaxf(tmx, red[k][2]);
            tmn = fminf(tmn, red[k][3]);
        }
        P[b * 128 + blockIdx.x] = make_float4(smx, smn, tmx, tmn);
    }
}

__device__ __forceinline__ float bspl(float d) {
    float ad = fabsf(d);
    float a = (3.0f * ad * ad * ad - 6.0f * ad * ad + 4.0f) * (1.0f / 6.0f);
    float t = 2.0f - ad;
    float c = t * t * t * (1.0f / 6.0f);
    return ad < 1.0f ? a : (ad < 2.0f ? c : 0.0f);
}

__device__ __forceinline__ void vox1(float sv, float tv, unsigned* jh,
                                     float spad, float sinv, float tpad,
                                     float tinv) {
    float posS = (sv - spad) * sinv;
    float fS = floorf(posS);
    fS = fminf(fmaxf(fS, 2.0f), 65.0f);
    int si = (int)fS - 1;
    float dS = posS - fS;
    float a[4] = {bspl(dS + 1.0f), bspl(dS), bspl(dS - 1.0f), bspl(dS - 2.0f)};

    float posT = (tv - tpad) * tinv;
    float fT = floorf(posT);
    fT = fminf(fmaxf(fT, 2.0f), 65.0f);
    int ti = (int)fT - 1;
    float dT = posT - fT;
    float bb[4] = {bspl(dT + 1.0f), bspl(dT), bspl(dT - 1.0f), bspl(dT - 2.0f)};

    unsigned* base = jh + si * NB + ti;
#pragma unroll
    for (int r = 0; r < 4; ++r) {
#pragma unroll
        for (int c = 0; c < 4; ++c) {
            unsigned q = (unsigned)(a[r] * bb[c] * SCALE + 0.5f);
            atomicAdd(&base[r * NB + c], q);
        }
    }
}

// Kernel 2: round-11 geometry (128 blocks/batch, 8 voxels/thread) with
// LANE-interleaved LDS copies (copy = lane&1): within one ds_add the even
// and odd lanes land NJ apart (NJ%32==16 -> bank+16), halving the lanes
// that can collide on a hot bin. Per-copy max 2048 vox * 0.4444 * 2^21 =
// 1.9e9 < 2^32. Plain coalesced u32 flush, no global atomics.
__global__ __launch_bounds__(HTHREADS) void k_hist(
    const float* __restrict__ src, const float* __restrict__ tgt,
    const float4* __restrict__ P, unsigned* __restrict__ H, int n4) {
    __shared__ unsigned lh[2 * NJ];
    __shared__ float pmm[8], mmv[4];
    const int tid = threadIdx.x;
    const int b = blockIdx.y;

    // inline reduce of the 125 minmax partials (2 waves)
    if (tid < 128) {
        float smx = -FLT_MAX, smn = FLT_MAX, tmx = -FLT_MAX, tmn = FLT_MAX;
        if (tid < MMBLK) {
            float4 v = P[b * 128 + tid];
            smx = v.x; smn = v.y; tmx = v.z; tmn = v.w;
        }
#pragma unroll
        for (int m = 1; m < 64; m <<= 1) {
            smx = fmaxf(smx, __shfl_xor(smx, m));
            smn = fminf(smn, __shfl_xor(smn, m));
            tmx = fmaxf(tmx, __shfl_xor(tmx, m));
            tmn = fminf(tmn, __shfl_xor(tmn, m));
        }
        if ((tid & 63) == 0) {
            int w = tid >> 6;
            pmm[w * 4 + 0] = smx;
            pmm[w * 4 + 1] = smn;
            pmm[w * 4 + 2] = tmx;
            pmm[w * 4 + 3] = tmn;
        }
    }
    // zero LDS hist concurrently
    uint4* z4 = (uint4*)lh;
    const uint4 zz = make_uint4(0u, 0u, 0u, 0u);
    for (int i = tid; i < (2 * NJ) / 4; i += HTHREADS) z4[i] = zz;
    __syncthreads();
    if (tid == 0) {
        mmv[0] = fmaxf(pmm[0], pmm[4]);   // smx
        mmv[1] = fminf(pmm[1], pmm[5]);   // smn
        mmv[2] = fmaxf(pmm[2], pmm[6]);   // tmx
        mmv[3] = fminf(pmm[3], pmm[7]);   // tmn
    }
    __syncthreads();

    const float sbw = (mmv[0] - mmv[1]) * (1.0f / 64.0f);
    const float tbw = (mmv[2] - mmv[3]) * (1.0f / 64.0f);
    const float sinv = 1.0f / sbw, tinv = 1.0f / tbw;
    const float spad = mmv[1] - 2.0f * sbw;
    const float tpad = mmv[3] - 2.0f * tbw;

    unsigned* jh = lh + (tid & 1) * NJ;    // lane-interleaved copies
    const float4* s4 = (const float4*)src + (size_t)b * n4;
    const float4* t4 = (const float4*)tgt + (size_t)b * n4;
    const int STRIDE = HBLK * HTHREADS;    // 65536 float4s
    const int i0 = blockIdx.x * HTHREADS + tid;
    const int i1 = i0 + STRIDE;

    float4 sA = s4[i0], tA = t4[i0];
    bool has2 = i1 < n4;
    float4 sB, tB;
    if (has2) { sB = s4[i1]; tB = t4[i1]; }

    vox1(sA.x, tA.x, jh, spad, sinv, tpad, tinv);
    vox1(sA.y, tA.y, jh, spad, sinv, tpad, tinv);
    vox1(sA.z, tA.z, jh, spad, sinv, tpad, tinv);
    vox1(sA.w, tA.w, jh, spad, sinv, tpad, tinv);
    if (has2) {
        vox1(sB.x, tB.x, jh, spad, sinv, tpad, tinv);
        vox1(sB.y, tB.y, jh, spad, sinv, tpad, tinv);
        vox1(sB.z, tB.z, jh, spad, sinv, tpad, tinv);
        vox1(sB.w, tB.w, jh, spad, sinv, tpad, tinv);
    }
    for (int i = i0 + 2 * STRIDE; i < n4; i += STRIDE) {   // generic tail
        float4 s = s4[i], t = t4[i];
        vox1(s.x, t.x, jh, spad, sinv, tpad, tinv);
        vox1(s.y, t.y, jh, spad, sinv, tpad, tinv);
        vox1(s.z, t.z, jh, spad, sinv, tpad, tinv);
        vox1(s.w, t.w, jh, spad, sinv, tpad, tinv);
    }
    __syncthreads();

    unsigned* Hb = H + (size_t)(b * HBLK + blockIdx.x) * NJ;
    for (int i = tid; i < NJ; i += HTHREADS) Hb[i] = lh[i] + lh[NJ + i];
}

// Kernel 3: 128-way per-bin sum with MLP by construction. 256 threads =
// 32 bins x 8 chunks of 16 rows; each thread issues 16 INDEPENDENT loads
// (fully unrolled, one latency wait), LDS u64 tree per bin, coalesced J
// write. Integer addition exact -> J bit-identical.
__global__ __launch_bounds__(256) void k_reduce(const unsigned* __restrict__ H,
                                                unsigned long long* __restrict__ J) {
    __shared__ unsigned long long part[8][32];
    const int b = blockIdx.y;
    const int binL = threadIdx.x & 31;          // bin within tile
    const int chunk = threadIdx.x >> 5;         // 0..7 -> rows chunk*16..+15
    const int bin = blockIdx.x * 32 + binL;
    const unsigned* Hb = H + (size_t)b * HBLK * NJ;

    unsigned long long s = 0ull;
    if (bin < NJ) {
        const unsigned* p = Hb + (size_t)chunk * 16 * NJ + bin;
#pragma unroll
        for (int k = 0; k < 16; ++k) s += p[(size_t)k * NJ];
    }
    part[chunk][binL] = s;
    __syncthreads();
    if (threadIdx.x < 32 && bin < NJ) {
        unsigned long long t = part[0][binL];
#pragma unroll
        for (int c = 1; c < 8; ++c) t += part[c][binL];
        J[(size_t)b * NJ + bin] = t;
    }
}

// Kernel 4: normalize (1 block per batch).
__global__ __launch_bounds__(1024) void k_final(
    const unsigned long long* __restrict__ J, float* __restrict__ out) {
    __shared__ float jf[NJ];
    __shared__ float rs[NB], cs[NB];
    __shared__ float red[16];
    const int b = blockIdx.x, tid = threadIdx.x;
    const unsigned long long* Jb = J + (size_t)b * NJ;

    float part = 0.0f;
    for (int i = tid; i < NJ; i += 1024) {
        float f = (float)((double)Jb[i] * INV_SCALE);
        jf[i] = f;
        part += f;
    }
#pragma unroll
    for (int m = 1; m < 64; m <<= 1) part += __shfl_xor(part, m);
    if ((tid & 63) == 0) red[tid >> 6] = part;
    __syncthreads();

    if (tid < NB) {                      // row sums -> source hist
        float s = 0.0f;
        for (int j = 0; j < NB; ++j) s += jf[tid * NB + j];
        rs[tid] = s;
    }
    if (tid >= 128 && tid < 128 + NB) {  // col sums -> target hist
        int c = tid - 128;
        float s = 0.0f;
        for (int r = 0; r < NB; ++r) s += jf[r * NB + c];
        cs[c] = s;
    }
    __syncthreads();

    float jsum = 0.0f;
#pragma unroll
    for (int k = 0; k < 16; ++k) jsum += red[k];
    float ssum = 0.0f, tsum = 0.0f;
    for (int k = 0; k < NB; ++k) ssum += rs[k];
    for (int k = 0; k < NB; ++k) tsum += cs[k];
    const float sden = fmaxf(ssum, 1e-8f);
    const float tden = fmaxf(tsum, 1e-8f);
    const float jden = fmaxf(jsum, 1e-8f);

    if (tid < NB) out[b * NB + tid] = rs[tid] / sden;
    if (tid >= 128 && tid < 128 + NB)
        out[2 * NB + b * NB + (tid - 128)] = cs[tid - 128] / tden;
    for (int i = tid; i < NJ; i += 1024)
        out[4 * NB + b * NJ + i] = jf[i] / jden;
}

extern "C" void kernel_launch(void* const* d_in, const int* in_sizes, int n_in,
                              void* d_out, int out_size, void* d_ws,
                              size_t ws_size, hipStream_t stream) {
    const float* src = (const float*)d_in[0];
    const float* tgt = (const float*)d_in[1];
    float* out = (float*)d_out;
    float4* P = (float4*)((char*)d_ws + 64);
    unsigned long long* J = (unsigned long long*)((char*)d_ws + 4160);
    unsigned* H = (unsigned*)((char*)d_ws + 78144);
    const int n4 = (in_sizes[0] / 2) / 4;          // 128000

    k_prep<<<dim3(MMBLK, 2), dim3(1024), 0, stream>>>(src, tgt, P, n4);
    k_hist<<<dim3(HBLK, 2), dim3(HTHREADS), 0, stream>>>(src, tgt, P, H, n4);
    k_reduce<<<dim3((NJ + 31) / 32, 2), dim3(256), 0, stream>>>(H, J);
    k_final<<<dim3(2), dim3(1024), 0, stream>>>(J, out);
}